// Round 1
// baseline (520.540 us; speedup 1.0000x reference)
//
#include <hip/hip_runtime.h>

// DCT upsample: out[img] = M * x[img] * M^T,  M = E*D (960x768)
//   D[k][m] = 2*cos(pi*k*(2m+1)/1536)            (DCT-II, N=768, norm=None)
//   E[i][0] = 1/1920 ; E[i][k] = cos(pi*(2i+1)*k/1920)/960   (IDCT, M=960)
// All GEMMs: C[M x N] = A[M x K] * Bt[N x K]^T, bf16 inputs, fp32 accum (MFMA).

#define HW 768
#define OHW 960
#define NIMG 48
#define KSPL 2304  // 3*768 for hi/lo split of M=E*D

typedef __attribute__((ext_vector_type(8))) short short8;
typedef __attribute__((ext_vector_type(4))) float f32x4;

__device__ __forceinline__ unsigned short f2bf(float f) {
    union { float f; unsigned int u; } v; v.f = f;
    unsigned int u = v.u;
    return (unsigned short)((u + 0x7FFFu + ((u >> 16) & 1u)) >> 16);
}
__device__ __forceinline__ float bf2f(unsigned short h) {
    union { unsigned int u; float f; } v; v.u = ((unsigned int)h) << 16;
    return v.f;
}

// ---------------- fill kernels ----------------
// Et: [960][2304] bf16 : [E_hi | E_hi | E_lo]
__global__ void fill_Et(unsigned short* __restrict__ Et) {
    int idx = blockIdx.x * 256 + threadIdx.x;
    if (idx >= OHW * KSPL) return;
    int i = idx / KSPL, k = idx % KSPL;
    int k0 = k % HW;
    float e;
    if (k0 == 0) {
        e = 1.0f / 1920.0f;
    } else {
        int r = ((2 * i + 1) * k0) % 3840;  // angle mod 2*pi, exact integer reduction
        e = cosf((float)r * (float)(3.14159265358979323846 / 1920.0)) * (1.0f / 960.0f);
    }
    unsigned short hi = f2bf(e);
    unsigned short outv;
    if (k < 1536) outv = hi;
    else          outv = f2bf(e - bf2f(hi));
    Et[idx] = outv;
}

// Dt: [768][2304] bf16 : columns n of D, K-blocks [D_hi | D_lo | D_hi]
__global__ void fill_Dt(unsigned short* __restrict__ Dt) {
    int idx = blockIdx.x * 256 + threadIdx.x;
    if (idx >= HW * KSPL) return;
    int n = idx / KSPL, k = idx % KSPL;
    int k0 = k % HW;
    int r = (k0 * (2 * n + 1)) % 3072;  // angle mod 2*pi
    float d = 2.0f * cosf((float)r * (float)(3.14159265358979323846 / 1536.0));
    unsigned short hi = f2bf(d);
    unsigned short outv;
    if (k < 768)       outv = hi;
    else if (k < 1536) outv = f2bf(d - bf2f(hi));
    else               outv = hi;
    Dt[idx] = outv;
}

// ---------------- transpose + fp32->bf16 convert ----------------
// xT[img][w][h] = x[img][h][w]
__global__ void transpose_conv(const float* __restrict__ x, unsigned short* __restrict__ xT) {
    __shared__ float tile[32][33];
    int img = blockIdx.z;
    int h0 = blockIdx.y * 32, w0 = blockIdx.x * 32;
    const float* xi = x + (size_t)img * HW * HW;
    unsigned short* xo = xT + (size_t)img * HW * HW;
    int tx = threadIdx.x, ty = threadIdx.y;  // (32,8)
#pragma unroll
    for (int r = 0; r < 4; ++r)
        tile[ty + 8 * r][tx] = xi[(size_t)(h0 + ty + 8 * r) * HW + (w0 + tx)];
    __syncthreads();
#pragma unroll
    for (int r = 0; r < 4; ++r)
        xo[(size_t)(w0 + ty + 8 * r) * HW + (h0 + tx)] = f2bf(tile[tx][ty + 8 * r]);
}

// ---------------- MFMA GEMM (B-transposed, K-major operands) ----------------
// C[M x N] = A[M x K] * Bt[N x K]^T
// block tile 128x128, BK=32, 4 waves (2x2), each wave 64x64 = 4x4 mfma_16x16x32 tiles
__global__ __launch_bounds__(256) void gemm_bt(
    const unsigned short* __restrict__ Ag, long long strideA, int lda,
    const unsigned short* __restrict__ Bg, long long strideB, int ldb,
    void* __restrict__ Cg, long long strideC, int ldc,
    int Md, int Nd, int Kd, int out_f32)
{
    __shared__ unsigned short As[128 * 32];
    __shared__ unsigned short Bs[128 * 32];

    const int tid = threadIdx.x;
    const int wave = tid >> 6, lane = tid & 63;
    const int wm = wave >> 1, wn = wave & 1;
    const int t16 = lane & 15, quad = lane >> 4;
    const int z = blockIdx.z;

    const unsigned short* A = Ag + (size_t)z * strideA;
    const unsigned short* B = Bg + (size_t)z * strideB;
    const int mb = blockIdx.y * 128, nbb = blockIdx.x * 128;

    f32x4 acc[4][4];
#pragma unroll
    for (int i = 0; i < 4; ++i)
#pragma unroll
        for (int j = 0; j < 4; ++j)
            acc[i][j] = (f32x4){0.f, 0.f, 0.f, 0.f};

    const int rowT = tid >> 2;          // 0..63
    const int kcT = (tid & 3) << 3;     // 0,8,16,24

    for (int k0 = 0; k0 < Kd; k0 += 32) {
#pragma unroll
        for (int it = 0; it < 2; ++it) {
            int row = rowT + it * 64;
            int gr = mb + row; if (gr >= Md) gr = Md - 1;
            short8 av = *(const short8*)(A + (size_t)gr * lda + k0 + kcT);
            *(short8*)(&As[row * 32 + kcT]) = av;
            int gn = nbb + row; if (gn >= Nd) gn = Nd - 1;
            short8 bv = *(const short8*)(B + (size_t)gn * ldb + k0 + kcT);
            *(short8*)(&Bs[row * 32 + kcT]) = bv;
        }
        __syncthreads();

        short8 af[4], bfr[4];
#pragma unroll
        for (int mi = 0; mi < 4; ++mi)
            af[mi] = *(const short8*)(&As[(wm * 64 + mi * 16 + t16) * 32 + quad * 8]);
#pragma unroll
        for (int ni = 0; ni < 4; ++ni)
            bfr[ni] = *(const short8*)(&Bs[(wn * 64 + ni * 16 + t16) * 32 + quad * 8]);
#pragma unroll
        for (int mi = 0; mi < 4; ++mi)
#pragma unroll
            for (int ni = 0; ni < 4; ++ni)
                acc[mi][ni] = __builtin_amdgcn_mfma_f32_16x16x32_bf16(
                    af[mi], bfr[ni], acc[mi][ni], 0, 0, 0);
        __syncthreads();
    }

    // epilogue: D row = quad*4 + r, col = t16 within each 16x16 tile
    const int gr0 = mb + wm * 64;
    const int gc0 = nbb + wn * 64;
    if (out_f32) {
        float* C = (float*)Cg + (size_t)z * strideC;
#pragma unroll
        for (int mi = 0; mi < 4; ++mi)
#pragma unroll
            for (int ni = 0; ni < 4; ++ni) {
                int col = gc0 + ni * 16 + t16;
                if (col < Nd) {
#pragma unroll
                    for (int r = 0; r < 4; ++r) {
                        int rowg = gr0 + mi * 16 + quad * 4 + r;
                        if (rowg < Md) C[(size_t)rowg * ldc + col] = acc[mi][ni][r];
                    }
                }
            }
    } else {
        unsigned short* C = (unsigned short*)Cg + (size_t)z * strideC;
#pragma unroll
        for (int mi = 0; mi < 4; ++mi)
#pragma unroll
            for (int ni = 0; ni < 4; ++ni) {
                int col = gc0 + ni * 16 + t16;
                if (col < Nd) {
#pragma unroll
                    for (int r = 0; r < 4; ++r) {
                        int rowg = gr0 + mi * 16 + quad * 4 + r;
                        if (rowg < Md) C[(size_t)rowg * ldc + col] = f2bf(acc[mi][ni][r]);
                    }
                }
            }
    }
}

extern "C" void kernel_launch(void* const* d_in, const int* in_sizes, int n_in,
                              void* d_out, int out_size, void* d_ws, size_t ws_size,
                              hipStream_t stream) {
    const float* x = (const float*)d_in[0];
    float* out = (float*)d_out;
    char* ws = (char*)d_ws;

    size_t offEt = 0;
    size_t offDt = offEt + (size_t)OHW * KSPL * 2;           // 4,423,680
    size_t offM  = offDt + (size_t)HW * KSPL * 2;            // +3,538,944
    size_t fixed = offM + (size_t)OHW * HW * 2;              // +1,474,560
    size_t perImg = (size_t)HW * HW * 2 + (size_t)OHW * HW * 2;

    int nb = 1;
    if (ws_size > fixed + perImg) {
        size_t q = (ws_size - fixed) / perImg;
        nb = (q > 48) ? 48 : (int)q;
        if (nb < 1) nb = 1;
    }

    unsigned short* Et = (unsigned short*)(ws + offEt);
    unsigned short* Dt = (unsigned short*)(ws + offDt);
    unsigned short* Mb = (unsigned short*)(ws + offM);
    unsigned short* xT = (unsigned short*)(ws + fixed);
    unsigned short* T  = (unsigned short*)(ws + fixed + (size_t)nb * HW * HW * 2);

    fill_Et<<<(OHW * KSPL + 255) / 256, 256, 0, stream>>>(Et);
    fill_Dt<<<(HW * KSPL + 255) / 256, 256, 0, stream>>>(Dt);

    // M = E * D   (960 x 768, K = 2304 split)  -> bf16
    gemm_bt<<<dim3(6, 8, 1), 256, 0, stream>>>(
        Et, 0, KSPL, Dt, 0, KSPL, Mb, 0, HW, OHW, HW, KSPL, 0);

    for (int b0 = 0; b0 < NIMG; b0 += nb) {
        int cur = NIMG - b0; if (cur > nb) cur = nb;
        // xT = transpose(x[b0..b0+cur]) in bf16
        transpose_conv<<<dim3(24, 24, cur), dim3(32, 8), 0, stream>>>(
            x + (size_t)b0 * HW * HW, xT);
        // T = M * x   (A = M, Bt = xT)
        gemm_bt<<<dim3(6, 8, cur), 256, 0, stream>>>(
            Mb, 0, HW, xT, (long long)HW * HW, HW,
            T, (long long)OHW * HW, HW, OHW, HW, HW, 0);
        // out = T * M^T  (A = T, Bt = M)
        gemm_bt<<<dim3(8, 8, cur), 256, 0, stream>>>(
            T, (long long)OHW * HW, HW, Mb, 0, HW,
            out + (size_t)b0 * OHW * OHW, (long long)OHW * OHW, OHW,
            OHW, OHW, HW, 1);
    }
    (void)in_sizes; (void)n_in; (void)out_size;
}

// Round 2
// 457.834 us; speedup vs baseline: 1.1370x; 1.1370x over previous
//
#include <hip/hip_runtime.h>

// DCT upsample: out[img] = M * x[img] * M^T,  M = E*D (960x768), closed-form
// via Dirichlet kernel:
//   M[i][n] = (1 + S(p1) + S(p2))/960,  S = sum_{k=1}^{767} cos(k*pi*p/7680)
//           = sin(767*pi*p/15360)*cos(768*pi*p/15360)/sin(pi*p/15360)
//   p1 = (8i+4)+(10n+5), p2 = (8i+4)-(10n+5)  (mod 15360, always odd -> no pole)
// GEMMs: C[M x N] = A[M x K] * Bt[N x K]^T, bf16 in, fp32 accum, MFMA 16x16x32,
// global_load_lds width-16 staging (LDS slot = tid*16B = wave base + lane*16).

#define HW 768
#define OHW 960
#define NIMG 48

typedef __attribute__((ext_vector_type(8))) short short8;
typedef __attribute__((ext_vector_type(4))) float f32x4;

__device__ __forceinline__ unsigned short f2bf(float f) {
    union { float f; unsigned int u; } v; v.f = f;
    unsigned int u = v.u;
    return (unsigned short)((u + 0x7FFFu + ((u >> 16) & 1u)) >> 16);
}

__device__ __forceinline__ void glds16(const void* g, void* l) {
    __builtin_amdgcn_global_load_lds(
        (const __attribute__((address_space(1))) void*)g,
        (__attribute__((address_space(3))) void*)l, 16, 0, 0);
}

// ---------------- closed-form M fill ----------------
__device__ __forceinline__ float dsum(int p) {
    // S = sum_{k=1}^{767} cos(k * pi * p / 7680), p in (0,15360), p odd
    int n1 = (767 * p) % 30720;
    int n2 = (768 * p) % 30720;
    const float w = (float)(3.14159265358979323846 / 15360.0);
    float s1 = sinf((float)n1 * w);
    float c2 = cosf((float)n2 * w);
    float s3 = sinf((float)p * w);
    return s1 * c2 / s3;
}

__global__ void fill_M(unsigned short* __restrict__ Mb) {
    int idx = blockIdx.x * 256 + threadIdx.x;
    if (idx >= OHW * HW) return;
    int i = idx / HW, n = idx - i * HW;
    int a = 8 * i + 4, b = 10 * n + 5;
    int p1 = a + b;                       // < 15360 always
    int p2 = a - b; if (p2 < 0) p2 += 15360;
    float m = (1.0f + dsum(p1) + dsum(p2)) * (1.0f / 960.0f);
    Mb[idx] = f2bf(m);
}

// ---------------- transpose + fp32->bf16 convert ----------------
__global__ void transpose_conv(const float* __restrict__ x, unsigned short* __restrict__ xT) {
    __shared__ float tile[32][33];
    int img = blockIdx.z;
    int h0 = blockIdx.y * 32, w0 = blockIdx.x * 32;
    const float* xi = x + (size_t)img * HW * HW;
    unsigned short* xo = xT + (size_t)img * HW * HW;
    int tx = threadIdx.x, ty = threadIdx.y;  // (32,8)
#pragma unroll
    for (int r = 0; r < 4; ++r)
        tile[ty + 8 * r][tx] = xi[(size_t)(h0 + ty + 8 * r) * HW + (w0 + tx)];
    __syncthreads();
#pragma unroll
    for (int r = 0; r < 4; ++r)
        xo[(size_t)(w0 + ty + 8 * r) * HW + (h0 + tx)] = f2bf(tile[tx][ty + 8 * r]);
}

// ---------------- MFMA GEMM (B-transposed, K-major operands) ----------------
// block tile 128x128, BK=32, 4 waves (2x2), each wave 64x64 = 4x4 mfma_16x16x32
__global__ __launch_bounds__(256) void gemm_bt(
    const unsigned short* __restrict__ Ag, long long strideA, int lda,
    const unsigned short* __restrict__ Bg, long long strideB, int ldb,
    void* __restrict__ Cg, long long strideC, int ldc,
    int Md, int Nd, int Kd, int out_f32)
{
    __shared__ unsigned short As[128 * 32];
    __shared__ unsigned short Bs[128 * 32];

    const int tid = threadIdx.x;
    const int wave = tid >> 6, lane = tid & 63;
    const int wm = wave >> 1, wn = wave & 1;
    const int t16 = lane & 15, quad = lane >> 4;
    const int z = blockIdx.z;

    const unsigned short* A = Ag + (size_t)z * strideA;
    const unsigned short* B = Bg + (size_t)z * strideB;
    const int mb = blockIdx.y * 128, nbb = blockIdx.x * 128;

    f32x4 acc[4][4];
#pragma unroll
    for (int i = 0; i < 4; ++i)
#pragma unroll
        for (int j = 0; j < 4; ++j)
            acc[i][j] = (f32x4){0.f, 0.f, 0.f, 0.f};

    const int rowT = tid >> 2;          // 0..63
    const int kcT = (tid & 3) << 3;     // 0,8,16,24
    // LDS byte slot for this thread's 16B = tid*16 = (wave*1024 + lane*16):
    // pass wave-uniform base, HW scatters lane*16.
    unsigned short* lA0 = As + wave * 512;   // +it*2048 shorts (=4096B) for rows 64..127
    unsigned short* lB0 = Bs + wave * 512;

    for (int k0 = 0; k0 < Kd; k0 += 32) {
#pragma unroll
        for (int it = 0; it < 2; ++it) {
            int row = rowT + it * 64;
            int gr = mb + row; if (gr >= Md) gr = Md - 1;
            glds16(A + (size_t)gr * lda + k0 + kcT, lA0 + it * 2048);
            int gn = nbb + row; if (gn >= Nd) gn = Nd - 1;
            glds16(B + (size_t)gn * ldb + k0 + kcT, lB0 + it * 2048);
        }
        __syncthreads();

        short8 af[4], bfr[4];
#pragma unroll
        for (int mi = 0; mi < 4; ++mi)
            af[mi] = *(const short8*)(&As[(wm * 64 + mi * 16 + t16) * 32 + quad * 8]);
#pragma unroll
        for (int ni = 0; ni < 4; ++ni)
            bfr[ni] = *(const short8*)(&Bs[(wn * 64 + ni * 16 + t16) * 32 + quad * 8]);
#pragma unroll
        for (int mi = 0; mi < 4; ++mi)
#pragma unroll
            for (int ni = 0; ni < 4; ++ni)
                acc[mi][ni] = __builtin_amdgcn_mfma_f32_16x16x32_bf16(
                    af[mi], bfr[ni], acc[mi][ni], 0, 0, 0);
        __syncthreads();
    }

    // epilogue: D row = quad*4 + r, col = t16 within each 16x16 tile
    const int gr0 = mb + wm * 64;
    const int gc0 = nbb + wn * 64;
    if (out_f32) {
        float* C = (float*)Cg + (size_t)z * strideC;
#pragma unroll
        for (int mi = 0; mi < 4; ++mi)
#pragma unroll
            for (int ni = 0; ni < 4; ++ni) {
                int col = gc0 + ni * 16 + t16;
                if (col < Nd) {
#pragma unroll
                    for (int r = 0; r < 4; ++r) {
                        int rowg = gr0 + mi * 16 + quad * 4 + r;
                        if (rowg < Md) C[(size_t)rowg * ldc + col] = acc[mi][ni][r];
                    }
                }
            }
    } else {
        unsigned short* C = (unsigned short*)Cg + (size_t)z * strideC;
#pragma unroll
        for (int mi = 0; mi < 4; ++mi)
#pragma unroll
            for (int ni = 0; ni < 4; ++ni) {
                int col = gc0 + ni * 16 + t16;
                if (col < Nd) {
#pragma unroll
                    for (int r = 0; r < 4; ++r) {
                        int rowg = gr0 + mi * 16 + quad * 4 + r;
                        if (rowg < Md) C[(size_t)rowg * ldc + col] = f2bf(acc[mi][ni][r]);
                    }
                }
            }
    }
}

extern "C" void kernel_launch(void* const* d_in, const int* in_sizes, int n_in,
                              void* d_out, int out_size, void* d_ws, size_t ws_size,
                              hipStream_t stream) {
    const float* x = (const float*)d_in[0];
    float* out = (float*)d_out;
    char* ws = (char*)d_ws;

    size_t offM  = 0;
    size_t fixed = offM + (size_t)OHW * HW * 2;              // 1,474,560 B
    size_t perImg = (size_t)HW * HW * 2 + (size_t)OHW * HW * 2;

    int nb = 1;
    if (ws_size > fixed + perImg) {
        size_t q = (ws_size - fixed) / perImg;
        nb = (q > 48) ? 48 : (int)q;
        if (nb < 1) nb = 1;
    }

    unsigned short* Mb = (unsigned short*)(ws + offM);
    unsigned short* xT = (unsigned short*)(ws + fixed);
    unsigned short* T  = (unsigned short*)(ws + fixed + (size_t)nb * HW * HW * 2);

    fill_M<<<(OHW * HW + 255) / 256, 256, 0, stream>>>(Mb);

    for (int b0 = 0; b0 < NIMG; b0 += nb) {
        int cur = NIMG - b0; if (cur > nb) cur = nb;
        // xT = transpose(x[b0..b0+cur]) in bf16
        transpose_conv<<<dim3(24, 24, cur), dim3(32, 8), 0, stream>>>(
            x + (size_t)b0 * HW * HW, xT);
        // T = M * x   (A = M, Bt = xT)
        gemm_bt<<<dim3(6, 8, cur), 256, 0, stream>>>(
            Mb, 0, HW, xT, (long long)HW * HW, HW,
            T, (long long)OHW * HW, HW, OHW, HW, HW, 0);
        // out = T * M^T  (A = T, Bt = M)
        gemm_bt<<<dim3(8, 8, cur), 256, 0, stream>>>(
            T, (long long)OHW * HW, HW, Mb, 0, HW,
            out + (size_t)b0 * OHW * OHW, (long long)OHW * OHW, OHW,
            OHW, OHW, HW, 1);
    }
    (void)in_sizes; (void)n_in; (void)out_size;
}

// Round 3
// 428.650 us; speedup vs baseline: 1.2144x; 1.0681x over previous
//
#include <hip/hip_runtime.h>

// DCT upsample: out[img] = M * x[img] * M^T,  M = E*D (960x768), closed-form
// Dirichlet kernel:
//   M[i][n] = (1 + S(p1) + S(p2))/960,  S = sin(767u)cos(768u)/sin(u), u=pi*p/15360
// Restructured so M is the A operand of BOTH gemms:
//   T' = M * x^T      (Bt = x row-major, bf16-converted)   [960 x 768]
//   out = M * T'^T    (Bt = T')                            [960 x 960]
// GEMM: C = A * Bt^T, bf16, fp32 accum, mfma 16x16x32, glds width-16 staging,
// XOR chunk swizzle (phys chunk c holds global chunk c ^ ((row>>1)&3)) to kill
// fragment-read bank conflicts.

#define HW 768
#define OHW 960
#define NIMG 48

typedef __attribute__((ext_vector_type(8))) short short8;
typedef __attribute__((ext_vector_type(4))) float f32x4;
typedef __attribute__((ext_vector_type(4))) float float4v;
typedef __attribute__((ext_vector_type(4))) unsigned short us4;

__device__ __forceinline__ unsigned short f2bf(float f) {
    union { float f; unsigned int u; } v; v.f = f;
    unsigned int u = v.u;
    return (unsigned short)((u + 0x7FFFu + ((u >> 16) & 1u)) >> 16);
}

__device__ __forceinline__ void glds16(const void* g, void* l) {
    __builtin_amdgcn_global_load_lds(
        (const __attribute__((address_space(1))) void*)g,
        (__attribute__((address_space(3))) void*)l, 16, 0, 0);
}

// ---------------- closed-form M fill ----------------
__device__ __forceinline__ float dsum(int p) {
    int n1 = (767 * p) % 30720;
    int n2 = (768 * p) % 30720;
    const float w = (float)(3.14159265358979323846 / 15360.0);
    return sinf((float)n1 * w) * cosf((float)n2 * w) / sinf((float)p * w);
}

__global__ void fill_M(unsigned short* __restrict__ Mb) {
    int idx = blockIdx.x * 256 + threadIdx.x;
    if (idx >= OHW * HW) return;
    int i = idx / HW, n = idx - i * HW;
    int a = 8 * i + 4, b = 10 * n + 5;
    int p1 = a + b;
    int p2 = a - b; if (p2 < 0) p2 += 15360;
    float m = (1.0f + dsum(p1) + dsum(p2)) * (1.0f / 960.0f);
    Mb[idx] = f2bf(m);
}

// ---------------- streaming f32 -> bf16 convert ----------------
__global__ void conv_bf16(const float* __restrict__ x, unsigned short* __restrict__ xb, int n4) {
    int i = blockIdx.x * 256 + threadIdx.x;
    if (i >= n4) return;
    float4v v = *(const float4v*)(x + (size_t)i * 4);
    us4 o; o.x = f2bf(v.x); o.y = f2bf(v.y); o.z = f2bf(v.z); o.w = f2bf(v.w);
    *(us4*)(xb + (size_t)i * 4) = o;
}

// ---------------- MFMA GEMM (B-transposed, K-major operands) ----------------
// block tile 128x128, BK=32, 4 waves (2x2), each wave 64x64 = 4x4 mfma_16x16x32
__global__ __launch_bounds__(256) void gemm_bt(
    const unsigned short* __restrict__ A, int lda,
    const unsigned short* __restrict__ Bg, long long strideB, int ldb,
    void* __restrict__ Cg, long long strideC, int ldc,
    int Md, int Nd, int Kd, int out_f32)
{
    __shared__ unsigned short As[128 * 32];
    __shared__ unsigned short Bs[128 * 32];

    const int tid = threadIdx.x;
    const int wave = tid >> 6, lane = tid & 63;
    const int wm = wave >> 1, wn = wave & 1;
    const int t16 = lane & 15, quad = lane >> 4;
    const int z = blockIdx.z;

    const unsigned short* B = Bg + (size_t)z * strideB;
    const int mb = blockIdx.y * 128, nbb = blockIdx.x * 128;

    f32x4 acc[4][4];
#pragma unroll
    for (int i = 0; i < 4; ++i)
#pragma unroll
        for (int j = 0; j < 4; ++j)
            acc[i][j] = (f32x4){0.f, 0.f, 0.f, 0.f};

    const int rowT = tid >> 2;                              // 0..63
    const int ksw = (((tid & 3) ^ ((rowT >> 1) & 3)) << 3); // swizzled k-chunk (shorts)
    // glds dest: contiguous tid*16B inside each 64-row slab
    unsigned short* lA0 = As + wave * 512;
    unsigned short* lB0 = Bs + wave * 512;

    // staged global row indices (clamped)
    int grA0 = mb + rowT;        if (grA0 >= Md) grA0 = Md - 1;
    int grA1 = mb + rowT + 64;   if (grA1 >= Md) grA1 = Md - 1;
    int gnB0 = nbb + rowT;       if (gnB0 >= Nd) gnB0 = Nd - 1;
    int gnB1 = nbb + rowT + 64;  if (gnB1 >= Nd) gnB1 = Nd - 1;
    const unsigned short* pA0 = A + (size_t)grA0 * lda + ksw;
    const unsigned short* pA1 = A + (size_t)grA1 * lda + ksw;
    const unsigned short* pB0 = B + (size_t)gnB0 * ldb + ksw;
    const unsigned short* pB1 = B + (size_t)gnB1 * ldb + ksw;

    // fragment-read bases (shorts); physical chunk = quad ^ ((t16>>1)&3)
    const int quadx = quad ^ ((t16 >> 1) & 3);
    const int aBase = (wm * 64 + t16) * 32 + quadx * 8;
    const int bBase = (wn * 64 + t16) * 32 + quadx * 8;

    for (int k0 = 0; k0 < Kd; k0 += 32) {
        glds16(pA0 + k0, lA0);
        glds16(pA1 + k0, lA0 + 2048);
        glds16(pB0 + k0, lB0);
        glds16(pB1 + k0, lB0 + 2048);
        __syncthreads();

        short8 af[4], bfr[4];
#pragma unroll
        for (int mi = 0; mi < 4; ++mi)
            af[mi] = *(const short8*)(&As[aBase + mi * 512]);
#pragma unroll
        for (int ni = 0; ni < 4; ++ni)
            bfr[ni] = *(const short8*)(&Bs[bBase + ni * 512]);
#pragma unroll
        for (int mi = 0; mi < 4; ++mi)
#pragma unroll
            for (int ni = 0; ni < 4; ++ni)
                acc[mi][ni] = __builtin_amdgcn_mfma_f32_16x16x32_bf16(
                    af[mi], bfr[ni], acc[mi][ni], 0, 0, 0);
        __syncthreads();
    }

    // epilogue: D row = quad*4 + r, col = t16 within each 16x16 tile
    const int gr0 = mb + wm * 64;
    const int gc0 = nbb + wn * 64;
    if (out_f32) {
        float* C = (float*)Cg + (size_t)z * strideC;
#pragma unroll
        for (int mi = 0; mi < 4; ++mi)
#pragma unroll
            for (int ni = 0; ni < 4; ++ni) {
                int col = gc0 + ni * 16 + t16;
                if (col < Nd) {
#pragma unroll
                    for (int r = 0; r < 4; ++r) {
                        int rowg = gr0 + mi * 16 + quad * 4 + r;
                        if (rowg < Md) C[(size_t)rowg * ldc + col] = acc[mi][ni][r];
                    }
                }
            }
    } else {
        unsigned short* C = (unsigned short*)Cg + (size_t)z * strideC;
#pragma unroll
        for (int mi = 0; mi < 4; ++mi)
#pragma unroll
            for (int ni = 0; ni < 4; ++ni) {
                int col = gc0 + ni * 16 + t16;
                if (col < Nd) {
#pragma unroll
                    for (int r = 0; r < 4; ++r) {
                        int rowg = gr0 + mi * 16 + quad * 4 + r;
                        if (rowg < Md) C[(size_t)rowg * ldc + col] = f2bf(acc[mi][ni][r]);
                    }
                }
            }
    }
}

extern "C" void kernel_launch(void* const* d_in, const int* in_sizes, int n_in,
                              void* d_out, int out_size, void* d_ws, size_t ws_size,
                              hipStream_t stream) {
    const float* x = (const float*)d_in[0];
    float* out = (float*)d_out;
    char* ws = (char*)d_ws;

    size_t offM  = 0;
    size_t fixed = offM + (size_t)OHW * HW * 2;              // 1,474,560 B
    size_t perImg = (size_t)HW * HW * 2 + (size_t)OHW * HW * 2;

    int nb = 1;
    if (ws_size > fixed + perImg) {
        size_t q = (ws_size - fixed) / perImg;
        nb = (q > 48) ? 48 : (int)q;
        if (nb < 1) nb = 1;
    }

    unsigned short* Mb = (unsigned short*)(ws + offM);
    unsigned short* xb = (unsigned short*)(ws + fixed);
    unsigned short* T  = (unsigned short*)(ws + fixed + (size_t)nb * HW * HW * 2);

    fill_M<<<(OHW * HW + 255) / 256, 256, 0, stream>>>(Mb);

    for (int b0 = 0; b0 < NIMG; b0 += nb) {
        int cur = NIMG - b0; if (cur > nb) cur = nb;
        // xb = bf16(x[b0..b0+cur]), straight streaming convert (no transpose)
        int n4 = cur * (HW * HW / 4);
        conv_bf16<<<(n4 + 255) / 256, 256, 0, stream>>>(
            x + (size_t)b0 * HW * HW, xb, n4);
        // T' = M * x^T   (A = M [960x768], Bt = xb [768 rows x 768 K])
        gemm_bt<<<dim3(6, 8, cur), 256, 0, stream>>>(
            Mb, HW, xb, (long long)HW * HW, HW,
            T, (long long)OHW * HW, HW, OHW, HW, HW, 0);
        // out = M * T'^T (A = M, Bt = T' [960 rows x 768 K])
        gemm_bt<<<dim3(8, 8, cur), 256, 0, stream>>>(
            Mb, HW, T, (long long)OHW * HW, HW,
            out + (size_t)b0 * OHW * OHW, (long long)OHW * OHW, OHW,
            OHW, OHW, HW, 1);
    }
    (void)in_sizes; (void)n_in; (void)out_size;
}